// Round 11
// baseline (62.236 us; speedup 1.0000x reference)
//
#include <hip/hip_runtime.h>
#include <hip/hip_bf16.h>

typedef __attribute__((ext_vector_type(8))) short short8;
typedef __attribute__((ext_vector_type(4))) float f32x4;
typedef __attribute__((ext_vector_type(4))) unsigned int u32x4;

#define GG 4
#define CC 128
#define HH 112
#define WW 112
#define HWSZ (HH * WW)
#define TH 16
#define TW 16
#define HALO 18
#define NPIX (HALO * HALO)      // 324
#define XSTR 40                 // bf16 per pixel row in LDS: pad 32->40 (80B; b128 reads ~conflict-free)
#define NT 256
#define WK_ELEMS (4 * 9 * 16 * 32)   // wk_reord[g][u][t16][c32], taps 9..15 zero
#define WP_ELEMS (4 * 2 * 16 * 32)   // wp_reord[g][mt][o16][c32]
#define W_TOTAL (WK_ELEMS + WP_ELEMS)

// ---- weight reorder into MFMA A-fragment layout (bf16) ----
__global__ __launch_bounds__(256)
void reorder_weights(const float* __restrict__ w_kg, const float* __restrict__ w_pw,
                     unsigned short* __restrict__ ws)
{
    int idx = blockIdx.x * 256 + threadIdx.x;
    if (idx < WK_ELEMS) {
        int c = idx & 31, t = (idx >> 5) & 15, r = idx >> 9;
        int u = r % 9, g = r / 9;
        float v = (t < 9) ? w_kg[((g * 9 + t) * 32 + c) * 9 + u] : 0.0f;
        ws[idx] = __builtin_bit_cast(unsigned short, __float2bfloat16(v));
    } else if (idx < W_TOTAL) {
        int j = idx - WK_ELEMS;
        int c = j & 31, o = (j >> 5) & 15, mt = (j >> 9) & 1, g = j >> 10;
        float v = w_pw[(g * 32 + mt * 16 + o) * 32 + c];
        ws[idx] = __builtin_bit_cast(unsigned short, __float2bfloat16(v));
    }
}

// ---- per-thread weight fragments, loaded BEFORE staging (overlap global latency) ----
struct Frags {
    short8 afrag[9];
    short8 wpfrag[2];
    float bkv[4];
    float bpv[8];
};

__device__ __forceinline__ void load_frags(Frags& f,
    const unsigned short* __restrict__ wsw,
    const float* __restrict__ b_kg, const float* __restrict__ b_pw,
    int g, int tid)
{
    const int lane = tid & 63;
    const int px   = lane & 15;
    const int kb   = lane >> 4;

    #pragma unroll
    for (int u = 0; u < 9; ++u)
        f.afrag[u] = *(const short8*)(wsw + (((g * 9 + u) * 16 + px) * 32 + kb * 8));
    #pragma unroll
    for (int mt = 0; mt < 2; ++mt)
        f.wpfrag[mt] = *(const short8*)(wsw + WK_ELEMS + (((g * 2 + mt) * 16 + px) * 32 + kb * 8));

    const float* bk = b_kg + g * 9;
    const float* bp = b_pw + g * 32;
    #pragma unroll
    for (int e = 0; e < 4; ++e) {
        int t = 4 * kb + e;
        f.bkv[e] = bk[t < 9 ? t : 0];   // clamped; invalid taps never consumed
    }
    #pragma unroll
    for (int mt = 0; mt < 2; ++mt)
        #pragma unroll
        for (int e = 0; e < 4; ++e)
            f.bpv[mt * 4 + e] = bp[mt * 16 + 4 * kb + e];
}

// ---- compute body (proven kvl-roundtrip kv broadcast; NO ds_bpermute — r5/r9
//      A/B pinned a deterministic miscompute on bpermute-after-MFMA) ----
__device__ __forceinline__ void compute_tile(const Frags& f,
    float* __restrict__ out, unsigned short* xs, float* kvl,
    int g, int b, int h0, int w0, int tid)
{
    const int lane = tid & 63;
    const int wid  = tid >> 6;
    const int px   = lane & 15;
    const int kb   = lane >> 4;

    float* kvp = &kvl[(wid * 16 + px) * 12];
    const size_t obase = ((size_t)(b * CC + g * 32) * HH + h0) * WW + w0 + px;

    #pragma unroll 1
    for (int r = 0; r < 4; ++r) {
        const int py = wid * 4 + r;

        short8 bfrag[9];
        #pragma unroll
        for (int u = 0; u < 9; ++u) {
            int q = (py + u / 3) * HALO + (px + u % 3);
            bfrag[u] = *(const short8*)&xs[q * XSTR + kb * 8];
        }

        // stage 1: kv = Wk * P; C/D: col=lane&15 (pixel), row=4*kb+e (tap)
        f32x4 kv = {0.f, 0.f, 0.f, 0.f};
        #pragma unroll
        for (int u = 0; u < 9; ++u)
            kv = __builtin_amdgcn_mfma_f32_16x16x32_bf16(f.afrag[u], bfrag[u], kv, 0, 0, 0);

        // kv cross-lane roundtrip (+bias): lane holds taps 4*kb..4*kb+3 of pixel px
        if (kb < 2) {
            f32x4 kvb;
            #pragma unroll
            for (int i = 0; i < 4; ++i) kvb[i] = kv[i] + f.bkv[i];
            *(f32x4*)&kvp[4 * kb] = kvb;
        } else if (kb == 2) {
            kvp[8] = kv[0] + f.bkv[0];
        }
        f32x4 k03 = *(const f32x4*)&kvp[0];
        f32x4 k47 = *(const f32x4*)&kvp[4];
        float k8 = kvp[8];
        float kvv[9] = {k03.x, k03.y, k03.z, k03.w, k47.x, k47.y, k47.z, k47.w, k8};

        // stage 2: involution on VALU, reusing bfrag registers
        float m[8] = {0.f, 0.f, 0.f, 0.f, 0.f, 0.f, 0.f, 0.f};
        #pragma unroll
        for (int u = 0; u < 9; ++u) {
            u32x4 bu = __builtin_bit_cast(u32x4, bfrag[u]);
            #pragma unroll
            for (int w = 0; w < 4; ++w) {
                unsigned d = bu[w];
                float lo = __builtin_bit_cast(float, d << 16);
                float hi = __builtin_bit_cast(float, d & 0xffff0000u);
                m[2 * w]     = fmaf(lo, kvv[u], m[2 * w]);
                m[2 * w + 1] = fmaf(hi, kvv[u], m[2 * w + 1]);
            }
        }

        // stage 3: pointwise via MFMA; m already in B-fragment order (k = 8kb+j)
        unsigned pk[4];
        #pragma unroll
        for (int w = 0; w < 4; ++w) {
            unsigned slo = __builtin_bit_cast(unsigned short, __float2bfloat16(m[2 * w]));
            unsigned shi = __builtin_bit_cast(unsigned short, __float2bfloat16(m[2 * w + 1]));
            pk[w] = slo | (shi << 16);
        }
        short8 mfrag = __builtin_bit_cast(short8, (u32x4){pk[0], pk[1], pk[2], pk[3]});

        f32x4 zero = {0.f, 0.f, 0.f, 0.f};
        f32x4 o0 = __builtin_amdgcn_mfma_f32_16x16x32_bf16(f.wpfrag[0], mfrag, zero, 0, 0, 0);
        f32x4 o1 = __builtin_amdgcn_mfma_f32_16x16x32_bf16(f.wpfrag[1], mfrag, zero, 0, 0, 0);

        #pragma unroll
        for (int e = 0; e < 4; ++e) {
            int o = 4 * kb + e;
            out[obase + (size_t)o * HWSZ + (size_t)py * WW] = o0[e] + f.bpv[e];
            out[obase + (size_t)(o + 16) * HWSZ + (size_t)py * WW] = o1[e] + f.bpv[4 + e];
        }
    }
}

// ---- fused single-pass kernel: direct fp32->bf16 staging, no x_t round-trip ----
__global__ __launch_bounds__(NT, 4)
void invol_fused(const float* __restrict__ x,
                 const float* __restrict__ b_kg, const float* __restrict__ b_pw,
                 const unsigned short* __restrict__ ws, float* __restrict__ out)
{
    __shared__ unsigned short xs[NPIX * XSTR];   // 25,920 B
    __shared__ float kvl[4 * 16 * 12];           //  3,072 B -> 5 blocks/CU by LDS

    const int tile  = blockIdx.x;                // 49 tiles of 16x16
    const int tileh = tile / 7;
    const int tilew = tile - tileh * 7;
    const int g = blockIdx.y;
    const int b = blockIdx.z;
    const int h0 = tileh * TH;
    const int w0 = tilew * TW;
    const int tid = threadIdx.x;

    // weight fragments first: their global latency overlaps staging below
    Frags f;
    load_frags(f, ws, b_kg, b_pw, g, tid);

    const float* xg = x + (size_t)(b * CC + g * 32) * HWSZ;

    // ---- staging phase A: interior cols 1..16 as aligned float4 ----
    // 2304 tasks = 32c x 18r x 4slots, exactly 9/thread, no predicates.
    {
        float4 v[9];
        int qi[9], ci[9];
        #pragma unroll
        for (int k = 0; k < 9; ++k) {
            int t  = tid + 256 * k;
            int s  = t & 3;                      // slot: cols 1+4s .. 4+4s
            int cr = t >> 2;                     // 0..575
            int c  = (cr * 911) >> 14;           // cr/18 (verified magic for cr<576)
            int r  = cr - 18 * c;
            int gh = h0 - 1 + r;
            bool okr = (unsigned)gh < (unsigned)HH;
            int ghc = okr ? gh : 0;
            float4 vv = *(const float4*)(xg + (size_t)c * HWSZ + ghc * WW + w0 + 4 * s);
            if (!okr) vv = make_float4(0.f, 0.f, 0.f, 0.f);
            v[k]  = vv;
            qi[k] = r * HALO + 1 + 4 * s;        // pixel of col 1+4s
            ci[k] = c;
        }
        #pragma unroll
        for (int k = 0; k < 9; ++k) {
            unsigned short* d = &xs[qi[k] * XSTR + ci[k]];
            d[0 * XSTR] = __builtin_bit_cast(unsigned short, __float2bfloat16(v[k].x));
            d[1 * XSTR] = __builtin_bit_cast(unsigned short, __float2bfloat16(v[k].y));
            d[2 * XSTR] = __builtin_bit_cast(unsigned short, __float2bfloat16(v[k].z));
            d[3 * XSTR] = __builtin_bit_cast(unsigned short, __float2bfloat16(v[k].w));
        }
    }

    // ---- staging phase B: edge cols 0 and 17 (576 channel-pair tasks) ----
    {
        #pragma unroll
        for (int k = 0; k < 3; ++k) {
            int t = tid + 256 * k;
            if (t < 576) {
                int c2 = (t * 1821) >> 16;       // t/36 (verified magic for t<576)
                int re = t - 36 * c2;
                int e  = re & 1;                 // 0: col 0 (w0-1), 1: col 17 (w0+16)
                int r  = re >> 1;
                int gh = h0 - 1 + r;
                int gw = e ? (w0 + TW) : (w0 - 1);
                bool ok = ((unsigned)gh < (unsigned)HH) && ((unsigned)gw < (unsigned)WW);
                int ghc = ok ? gh : 0;
                int gwc = ok ? gw : 0;
                const float* p = xg + (size_t)(2 * c2) * HWSZ + ghc * WW + gwc;
                float a0 = p[0];
                float a1 = p[HWSZ];
                if (!ok) { a0 = 0.f; a1 = 0.f; }
                int q = r * HALO + (e ? 17 : 0);
                xs[q * XSTR + 2 * c2]     = __builtin_bit_cast(unsigned short, __float2bfloat16(a0));
                xs[q * XSTR + 2 * c2 + 1] = __builtin_bit_cast(unsigned short, __float2bfloat16(a1));
            }
        }
    }
    __syncthreads();

    compute_tile(f, out, xs, kvl, g, b, h0, w0, tid);
}

extern "C" void kernel_launch(void* const* d_in, const int* in_sizes, int n_in,
                              void* d_out, int out_size, void* d_ws, size_t ws_size,
                              hipStream_t stream)
{
    const float* x    = (const float*)d_in[0];
    const float* w_kg = (const float*)d_in[1];
    const float* b_kg = (const float*)d_in[2];
    const float* w_pw = (const float*)d_in[3];
    const float* b_pw = (const float*)d_in[4];
    float* out = (float*)d_out;
    unsigned short* ws = (unsigned short*)d_ws;

    int pre_blocks = (W_TOTAL + 255) / 256;      // 88 blocks, ~22.5K elems
    hipLaunchKernelGGL(reorder_weights, dim3(pre_blocks), dim3(256), 0, stream,
                       w_kg, w_pw, ws);
    hipLaunchKernelGGL(invol_fused, dim3(49, GG, 8), dim3(NT), 0, stream,
                       x, b_kg, b_pw, ws, out);
}